// Round 6
// baseline (169.727 us; speedup 1.0000x reference)
//
#include <hip/hip_runtime.h>
#include <math.h>

#define ALPHA 8.3f
#define SB 17408   // stage bytes per buffer: 136 slices (4r x 34c) * 8 granules * 16 B

typedef short v8s  __attribute__((ext_vector_type(8)));
typedef float v16f __attribute__((ext_vector_type(16)));
typedef float v4f  __attribute__((ext_vector_type(4)));

static __device__ __forceinline__ unsigned short f2bf(float f) {
    unsigned int u = __float_as_uint(f);
    u = (u + 0x7fffu + ((u >> 16) & 1u)) >> 16;   // RNE
    return (unsigned short)u;
}

static __device__ __forceinline__ void async16(const void* g, void* l) {
    __builtin_amdgcn_global_load_lds(
        (const __attribute__((address_space(1))) unsigned int*)g,
        (__attribute__((address_space(3))) unsigned int*)l, 16, 0, 0);
}

// Fused: blocks 0..511 = x cast fp32 NCHW -> bf16 NHWC; blocks 512..1663 =
// weight A-fragment pre-swizzle (verified R2-R5) + zbuf zeroing.
__global__ __launch_bounds__(256)
void prep_and_cast(const float* __restrict__ x, const float* __restrict__ wsrc,
                   unsigned short* __restrict__ wt, unsigned short* __restrict__ x2,
                   float* __restrict__ zbuf) {
    const int tid = threadIdx.x;
    if (blockIdx.x >= 512) {
        const int blk = blockIdx.x - 512;
        if (blk == 0) zbuf[tid] = 0.f;           // 256 floats zeroed (DMA halo target)
        int i = blk * 256 + tid;
        if (i < 9 * 32 * 2 * 64 * 8) {
            int j    = i & 7;
            int lane = (i >> 3) & 63;
            int mt   = (i >> 9) & 1;
            int ks   = (i >> 10) & 31;
            int tap  = i >> 15;
            int o = mt * 32 + (lane & 31);
            int c = ks * 16 + (lane >> 5) * 8 + j;
            wt[i] = f2bf(wsrc[(o * 512 + c) * 9 + tap]);
        }
        return;
    }
    // ---- cast: one (b,h) row per block; 16 chunks of 32 channels ----
    __shared__ float st[32 * 66];                // pitch 66: 2-way max on r/w (free)
    const int h = blockIdx.x & 63;
    const int b = blockIdx.x >> 6;
    const float* xb = x + ((size_t)b * 512) * 4096 + h * 64;
    unsigned short* ob = x2 + ((size_t)(b * 4096 + h * 64)) * 512;
    for (int cb = 0; cb < 16; ++cb) {
        __syncthreads();
#pragma unroll
        for (int j = 0; j < 2; ++j) {
            const int idx = j * 256 + tid;
            const int c = idx >> 4, w4 = (idx & 15) * 4;
            const float4 v = *(const float4*)&xb[(size_t)(cb * 32 + c) * 4096 + w4];
            *(float2*)&st[c * 66 + w4]     = make_float2(v.x, v.y);
            *(float2*)&st[c * 66 + w4 + 2] = make_float2(v.z, v.w);
        }
        __syncthreads();
        {
            const int w = tid >> 2, k = tid & 3;
            unsigned short t[8];
#pragma unroll
            for (int e = 0; e < 8; ++e) t[e] = f2bf(st[(k * 8 + e) * 66 + w]);
            uint4 u;
            u.x = t[0] | ((unsigned)t[1] << 16);
            u.y = t[2] | ((unsigned)t[3] << 16);
            u.z = t[4] | ((unsigned)t[5] << 16);
            u.w = t[6] | ((unsigned)t[7] << 16);
            *(uint4*)&ob[(size_t)w * 512 + cb * 32 + k * 8] = u;
        }
    }
}

// Main: 512 blocks (2/CU) x 256 thr. Block = (b, 2 rows, 32 cols), all 64 Cout.
// 4 waves = kh(2) x mt(2); each wave computes BOTH rows, A-frags cached across
// the staged-row loop (each tap-row loaded once), B-frags shared across rows.
__global__ __launch_bounds__(256, 2)
void depthconv_v6(const unsigned short* __restrict__ x2,
                  const float* __restrict__ depth,
                  const unsigned short* __restrict__ wt,
                  const float* __restrict__ zbuf,
                  float* __restrict__ out) {
    __shared__ __align__(16) char smem[2 * SB];   // 34,816 B; epilogue red reuses front

    const int bx  = blockIdx.x;
    const int xcd = bx & 7;                 // XCD swizzle: adjacent ht tiles share halo in L2
    const int i0  = bx >> 3;                // 0..63
    const int sub = i0 & 3;
    const int wt2 = (i0 >> 2) & 1;
    const int b   = i0 >> 3;                // 0..7
    const int ht  = xcd * 4 + sub;          // 0..31
    const int h0 = ht * 2, w0 = wt2 * 32;

    const int tid  = threadIdx.x;
    const int wid  = tid >> 6;
    const int lane = tid & 63;
    const int l31  = lane & 31;
    const int half = lane >> 5;
    const int kh   = wid & 1;               // channel half [kh*256, +256)
    const int mt   = wid >> 1;              // Cout 32-group

    const char* xpix = (const char*)x2 + ((size_t)b * 4096) * 1024;

    // ---- gates for rows h0, h0+1 (fp32; OOB depth = 0 — verified R2) ----
    float gt[2][9];
    {
        const float* dp = depth + (size_t)b * 4096;
#pragma unroll
        for (int r = 0; r < 2; ++r) {
            const int hq = h0 + r, wq = w0 + l31;
            const float d0 = dp[hq * 64 + wq];
#pragma unroll
            for (int t = 0; t < 9; ++t) {
                const int hn = hq + t / 3 - 1, wn = wq + t % 3 - 1;
                const float dn = (hn >= 0 && hn < 64 && wn >= 0 && wn < 64) ? dp[hn * 64 + wn] : 0.f;
                gt[r][t] = __expf(-ALPHA * fabsf(d0 - dn));
            }
        }
    }

    // ---- hoisted DMA source pointers (1088 granules / 256 thr -> 5 slots) ----
    // slot i: slice=i>>3 (r*34+c over rows h0-1..h0+2, cols w0-1..w0+32),
    // gg=(i&7)^(slice&7); content ch [(gg>>2)*256 + ss*32 + (gg&3)*8, +8)  [R5-verified]
    const char* gp[5];
#pragma unroll
    for (int it = 0; it < 5; ++it) {
        const int i = it * 256 + tid;
        const int slice = i >> 3;
        const int gg = (i & 7) ^ (slice & 7);
        const int r = slice / 34;
        const int c = slice - r * 34;
        const int hh = h0 - 1 + r, ww = w0 - 1 + c;
        gp[it] = (hh >= 0 && hh < 64 && ww >= 0 && ww < 64)
               ? xpix + (size_t)(hh * 64 + ww) * 1024 + (gg >> 2) * 512 + (gg & 3) * 16
               : (const char*)zbuf;
    }

#define ISSUE(SS)                                                              \
    {                                                                          \
        char* dst = smem + ((SS) & 1) * SB;                                    \
        _Pragma("unroll")                                                      \
        for (int it = 0; it < 5; ++it)                                         \
            if (it < 4 || tid < 64)                                            \
                async16(gp[it] + (SS) * 64, dst + (it * 256 + tid) * 16);      \
    }

    v16f acc[2];
    v16f vzero;
#pragma unroll
    for (int r = 0; r < 16; ++r) { acc[0][r] = 0.f; acc[1][r] = 0.f; vzero[r] = 0.f; }

    ISSUE(0);

    for (int ss = 0; ss < 8; ++ss) {
        __syncthreads();                    // drains DMA(ss); fences ss-1 LDS reads
        if (ss < 7) ISSUE(ss + 1);
        const char* buf = smem + (ss & 1) * SB;
        v8s aprev[3][2], acur[3][2];
#pragma unroll
        for (int s = 0; s < 4; ++s) {       // staged row s; serves out-rows r = s, s-1
            v8s bb[3][2];
#pragma unroll
            for (int dj = 0; dj < 3; ++dj) {
                const int slice = s * 34 + l31 + dj;
                const int s7 = slice & 7;
#pragma unroll
                for (int kk = 0; kk < 2; ++kk) {
                    const int g = kh * 4 + kk * 2 + half;
                    bb[dj][kk] = *(const v8s*)(buf + (size_t)((slice << 3) + (g ^ s7)) * 16);
                }
            }
            if (s < 3) {
#pragma unroll
                for (int dj = 0; dj < 3; ++dj)
#pragma unroll
                    for (int kk = 0; kk < 2; ++kk) {
                        const int tap = s * 3 + dj;
                        const int ks = kh * 16 + ss * 2 + kk;
                        acur[dj][kk] = *(const v8s*)&wt[(((tap * 32 + ks) * 2 + mt) * 64 + lane) * 8];
                    }
            }
            if (s < 3) {                    // r = 0, tap-row = s
#pragma unroll
                for (int dj = 0; dj < 3; ++dj) {
                    v16f pass = __builtin_amdgcn_mfma_f32_32x32x16_bf16(acur[dj][0], bb[dj][0], vzero, 0, 0, 0);
                    pass = __builtin_amdgcn_mfma_f32_32x32x16_bf16(acur[dj][1], bb[dj][1], pass, 0, 0, 0);
                    const float gv = gt[0][s * 3 + dj];
#pragma unroll
                    for (int r = 0; r < 16; ++r) acc[0][r] = fmaf(gv, pass[r], acc[0][r]);
                }
            }
            if (s >= 1) {                   // r = 1, tap-row = s-1 (A reused from prev s)
#pragma unroll
                for (int dj = 0; dj < 3; ++dj) {
                    v16f pass = __builtin_amdgcn_mfma_f32_32x32x16_bf16(aprev[dj][0], bb[dj][0], vzero, 0, 0, 0);
                    pass = __builtin_amdgcn_mfma_f32_32x32x16_bf16(aprev[dj][1], bb[dj][1], pass, 0, 0, 0);
                    const float gv = gt[1][(s - 1) * 3 + dj];
#pragma unroll
                    for (int r = 0; r < 16; ++r) acc[1][r] = fmaf(gv, pass[r], acc[1][r]);
                }
            }
#pragma unroll
            for (int dj = 0; dj < 3; ++dj)
#pragma unroll
                for (int kk = 0; kk < 2; ++kk) aprev[dj][kk] = acur[dj][kk];
        }
    }

    // ---- in-block kh reduction (pitch 80 B -> conflict-free), single store ----
    __syncthreads();
    float* red = (float*)smem;
    if (kh == 1) {
#pragma unroll
        for (int r = 0; r < 2; ++r)
#pragma unroll
            for (int qd = 0; qd < 4; ++qd) {
                v4f v;
                v[0] = acc[r][qd * 4];     v[1] = acc[r][qd * 4 + 1];
                v[2] = acc[r][qd * 4 + 2]; v[3] = acc[r][qd * 4 + 3];
                *(v4f*)&red[((mt * 2 + r) * 64 + lane) * 20 + qd * 4] = v;
            }
    }
    __syncthreads();
    if (kh == 0) {
#pragma unroll
        for (int r = 0; r < 2; ++r) {
            float* ob = out + ((size_t)b * 64) * 4096 + (h0 + r) * 64 + w0;
#pragma unroll
            for (int qd = 0; qd < 4; ++qd) {
                const v4f v = *(const v4f*)&red[((mt * 2 + r) * 64 + lane) * 20 + qd * 4];
#pragma unroll
                for (int j = 0; j < 4; ++j) {
                    const int rg = qd * 4 + j;
                    const int o = mt * 32 + (rg & 3) + 8 * (rg >> 2) + 4 * half;  // verified C-layout
                    ob[(size_t)o * 4096 + l31] = acc[r][rg] + v[j];
                }
            }
        }
    }
}

extern "C" void kernel_launch(void* const* d_in, const int* in_sizes, int n_in,
                              void* d_out, int out_size, void* d_ws, size_t ws_size,
                              hipStream_t stream) {
    const float* x      = (const float*)d_in[0];
    const float* depth  = (const float*)d_in[1];
    const float* weight = (const float*)d_in[2];
    float* out = (float*)d_out;

    unsigned short* wtb = (unsigned short*)d_ws;                        // 589,824 B
    float* zbuf         = (float*)((char*)d_ws + 786432);               // 1 KB zeros (halo)
    unsigned short* x2  = (unsigned short*)((char*)d_ws + (1 << 20));   // 33.6 MB bf16 NHWC

    prep_and_cast<<<1664, 256, 0, stream>>>(x, weight, wtb, x2, zbuf);
    depthconv_v6<<<512, 256, 0, stream>>>(x2, depth, wtb, zbuf, out);
}